// Round 2
// baseline (246.885 us; speedup 1.0000x reference)
//
#include <hip/hip_runtime.h>

#define AS1(p) ((const __attribute__((address_space(1))) void*)(p))
#define AS3(p) ((__attribute__((address_space(3))) void*)(p))

typedef unsigned short u16;
typedef __bf16 bf16x8 __attribute__((ext_vector_type(8)));
typedef short s16x8 __attribute__((ext_vector_type(8)));
typedef float f32x4 __attribute__((ext_vector_type(4)));
typedef unsigned short u16x4 __attribute__((ext_vector_type(4)));
typedef unsigned short u16x8v __attribute__((ext_vector_type(8)));

__device__ __forceinline__ u16 f2bf(float x) {
    unsigned u = __float_as_uint(x);
    unsigned r = (u + 0x7FFFu + ((u >> 16) & 1u)) >> 16;
    return (u16)r;
}

// ---- MFMA wrapper: tolerate either V8bf16 or V8i16 builtin signature ----
template <typename V8>
__device__ __forceinline__ auto mfma_sel(V8 a, V8 b, f32x4 c, int)
    -> decltype(__builtin_amdgcn_mfma_f32_16x16x32_bf16(a, b, c, 0, 0, 0))
{
    return __builtin_amdgcn_mfma_f32_16x16x32_bf16(a, b, c, 0, 0, 0);
}
template <typename V8>
__device__ __forceinline__ f32x4 mfma_sel(V8 a, V8 b, f32x4 c, long)
{
    s16x8 a2 = __builtin_bit_cast(s16x8, a);
    s16x8 b2 = __builtin_bit_cast(s16x8, b);
    return __builtin_amdgcn_mfma_f32_16x16x32_bf16(a2, b2, c, 0, 0, 0);
}
__device__ __forceinline__ f32x4 mfma16x16x32(bf16x8 a, bf16x8 b, f32x4 c)
{
    return mfma_sel(a, b, c, 0);
}

// ---------------- fp32 -> bf16 convert ----------------
__global__ __launch_bounds__(256) void cvt_bf16_kernel(const float* __restrict__ in,
                                                       u16* __restrict__ out, int n4)
{
    int i = blockIdx.x * 256 + threadIdx.x;
    if (i >= n4) return;
    float4 f = ((const float4*)in)[i];
    u16x4 o;
    o.x = f2bf(f.x); o.y = f2bf(f.y); o.z = f2bf(f.z); o.w = f2bf(f.w);
    ((u16x4*)out)[i] = o;
}

// ---------------- bf16 transpose: in[R][C] -> out[C][R], 64x64 tiles ----------------
__global__ __launch_bounds__(256) void transpose16(const u16* __restrict__ in,
                                                   u16* __restrict__ out, int R, int C)
{
    __shared__ u16 tl[64][65];   // pad 65: conflict-spread on transposed read
    const int tr0 = blockIdx.y * 64, tc0 = blockIdx.x * 64;
    const int t = threadIdx.x;
    const int r = t >> 2, c4 = (t & 3) << 4;

    const u16* src = in + (size_t)(tr0 + r) * C + tc0 + c4;
    u16x8v a0 = *(const u16x8v*)src;
    u16x8v a1 = *(const u16x8v*)(src + 8);
    #pragma unroll
    for (int j = 0; j < 8; ++j) { tl[r][c4 + j] = a0[j]; tl[r][c4 + 8 + j] = a1[j]; }
    __syncthreads();

    u16x8v b0, b1;
    #pragma unroll
    for (int j = 0; j < 8; ++j) { b0[j] = tl[c4 + j][r]; b1[j] = tl[c4 + 8 + j][r]; }
    u16* dst = out + (size_t)(tc0 + r) * R + tr0 + c4;
    *(u16x8v*)dst = b0;
    *(u16x8v*)(dst + 8) = b1;
}

// ---------------- NT GEMM: C[m][n] = sum_k A[m][k]*B[n][k] ----------------
// BIAS: 0 none, 1 bias[col], 3 fused-QKV epilogue (3 outputs by col segment).
// OUTBF16: output dtype. CSKIP: skip blocks above causal diagonal (scores).
// CKB: bound K at m0+BM (PV with causal-zeroed P); rows reversed so long
//      blocks dispatch first.
#define BM 128
#define BN 128
#define BK 64

template <int BIAS, int OUTBF16, int CSKIP, int CKB>
__global__ __launch_bounds__(256, 2)
void gemm_nt(const u16* __restrict__ A, const u16* __restrict__ B,
             void* __restrict__ Cv, const float* __restrict__ bias,
             void* __restrict__ C2, const float* __restrict__ bias2,
             void* __restrict__ C3, const float* __restrict__ bias3,
             int M, int N, int K, int lda, int ldb, int ldc,
             long long sA, long long sB, long long sC, float scale)
{
    __shared__ u16 lA[2][BM * BK];
    __shared__ u16 lB[2][BN * BK];

    int by = blockIdx.y;
    if (CKB) by = gridDim.y - 1 - by;       // longest-K blocks first
    const int m0 = by * BM;
    const int n0 = blockIdx.x * BN;
    if (CSKIP && n0 > m0 + BM - 1) return;

    const int z = blockIdx.z;
    A += (size_t)z * (size_t)sA;
    B += (size_t)z * (size_t)sB;

    const int t = threadIdx.x;
    const int lane = t & 63;
    const int w = t >> 6;
    const int wr = w >> 1, wc = w & 1;
    const int fr = lane & 15, fg = lane >> 4;

    int Keff = K;
    if (CKB) { Keff = m0 + BM; if (Keff > K) Keff = K; }
    const int nk = Keff / BK;

    f32x4 acc[4][4] = {};

    auto STAGE = [&](int k0, int buf) {
        #pragma unroll
        for (int p = 0; p < 4; ++p) {
            int e = (p * 4096 + t * 16) >> 1;   // element offset in tile
            int row = e >> 6;                   // /BK
            int col = e & (BK - 1);
            __builtin_amdgcn_global_load_lds(
                AS1(A + (size_t)(m0 + row) * lda + k0 + col), AS3(&lA[buf][e]), 16, 0, 0);
            __builtin_amdgcn_global_load_lds(
                AS1(B + (size_t)(n0 + row) * ldb + k0 + col), AS3(&lB[buf][e]), 16, 0, 0);
        }
    };

    STAGE(0, 0);
    __syncthreads();                  // drains vmcnt(0): buf0 staged

    int cur = 0;
    for (int it = 0; it < nk; ++it) {
        if (it + 1 < nk) STAGE((it + 1) * BK, cur ^ 1);   // prefetch under compute
        #pragma unroll
        for (int kk = 0; kk < BK; kk += 32) {
            bf16x8 af[4], bfr[4];
            #pragma unroll
            for (int mi = 0; mi < 4; ++mi)
                af[mi] = *(const bf16x8*)&lA[cur][(wr * 64 + mi * 16 + fr) * BK + kk + fg * 8];
            #pragma unroll
            for (int ni = 0; ni < 4; ++ni)
                bfr[ni] = *(const bf16x8*)&lB[cur][(wc * 64 + ni * 16 + fr) * BK + kk + fg * 8];
            #pragma unroll
            for (int mi = 0; mi < 4; ++mi)
                #pragma unroll
                for (int ni = 0; ni < 4; ++ni)
                    acc[mi][ni] = mfma16x16x32(af[mi], bfr[ni], acc[mi][ni]);
        }
        __syncthreads();              // drains vmcnt (prefetch done) + lgkm, barrier
        cur ^= 1;
    }

    // ---- epilogue: C/D layout col=lane&15, row=(lane>>4)*4+reg ----
    #pragma unroll
    for (int mi = 0; mi < 4; ++mi) {
        #pragma unroll
        for (int ni = 0; ni < 4; ++ni) {
            int col = n0 + wc * 64 + ni * 16 + fr;
            u16* dst16 = (u16*)Cv;
            float* dst32 = (float*)Cv;
            float bval = 0.f, sc_ = scale;
            int ccol = col;
            if (BIAS == 1) bval = bias[col];
            if (BIAS == 3) {
                int seg = col >> 10; ccol = col & 1023;
                if (seg == 0)      { dst16 = (u16*)Cv; bval = bias[ccol]; }
                else if (seg == 1) { dst16 = (u16*)C2; bval = bias2[ccol]; sc_ = 1.f; }
                else               { dst16 = (u16*)C3; bval = bias3[ccol]; sc_ = 1.f; }
            }
            #pragma unroll
            for (int j = 0; j < 4; ++j) {
                int row = m0 + wr * 64 + mi * 16 + fg * 4 + j;
                float v = (acc[mi][ni][j] + bval) * sc_;
                size_t off = (size_t)z * (size_t)sC + (size_t)row * ldc + ccol;
                if (OUTBF16 || BIAS == 3) dst16[off] = f2bf(v);
                else                      dst32[off] = v;
            }
        }
    }
}

// ---------------- causal softmax, in-place fp32 -> bf16 P ----------------
__device__ __forceinline__ float waveMax(float v) {
    #pragma unroll
    for (int o = 32; o > 0; o >>= 1) v = fmaxf(v, __shfl_xor(v, o));
    return v;
}
__device__ __forceinline__ float waveSum(float v) {
    #pragma unroll
    for (int o = 32; o > 0; o >>= 1) v += __shfl_xor(v, o);
    return v;
}

__global__ __launch_bounds__(256) void softmax_causal_kernel(float* __restrict__ scores, int S)
{
    __shared__ float red[4];
    const int gb = blockIdx.x;
    const int b = gb / S;
    const int i = gb - b * S;
    float* srow = scores + (size_t)b * S * S + (size_t)i * S;
    u16* prow = (u16*)srow;  // overwrite first half of the fp32 row with bf16 P
    const int t = threadIdx.x;
    const int jlim = ((i >> 7) + 1) << 7;   // computed-region end (tile-rounded)

    float vals[8];
    float mx = -1e30f;
    #pragma unroll
    for (int s = 0; s < 8; ++s) {
        int j = t + (s << 8);
        float x = -1e30f;
        if (j <= i) x = srow[j];
        vals[s] = x;
        mx = fmaxf(mx, x);
    }
    mx = waveMax(mx);
    const int wv = t >> 6;
    if ((t & 63) == 0) red[wv] = mx;
    __syncthreads();
    mx = fmaxf(fmaxf(red[0], red[1]), fmaxf(red[2], red[3]));
    __syncthreads();

    float sum = 0.f;
    #pragma unroll
    for (int s = 0; s < 8; ++s) {
        float e = (vals[s] > -1e29f) ? __expf(vals[s] - mx) : 0.f;
        vals[s] = e;
        sum += e;
    }
    sum = waveSum(sum);
    if ((t & 63) == 0) red[wv] = sum;
    __syncthreads();
    sum = red[0] + red[1] + red[2] + red[3];
    const float inv = 1.f / sum;
    __syncthreads();   // all reads of srow complete before aliased bf16 writes

    #pragma unroll
    for (int s = 0; s < 8; ++s) {
        int j = t + (s << 8);
        if (j < jlim) prow[j] = f2bf(vals[s] * inv);
    }
}

// ---------------- host launcher ----------------
extern "C" void kernel_launch(void* const* d_in, const int* in_sizes, int n_in,
                              void* d_out, int out_size, void* d_ws, size_t ws_size,
                              hipStream_t stream)
{
    (void)in_sizes; (void)n_in; (void)out_size;
    const float* x  = (const float*)d_in[0];
    const float* Wq = (const float*)d_in[1];
    const float* bq = (const float*)d_in[2];
    const float* Wk = (const float*)d_in[3];
    const float* bk = (const float*)d_in[4];
    const float* Wv = (const float*)d_in[5];
    const float* bv = (const float*)d_in[6];
    const float* Wp = (const float*)d_in[7];
    const float* bp = (const float*)d_in[8];

    const int D = 1024, S = 2048, B = 4;
    const int M = B * S; // 8192

    char* p = (char*)d_ws;
    u16* xb   = (u16*)p; p += (size_t)M * D * 2;        // 16 MB (aliased attnb later)
    u16* Wcat = (u16*)p; p += (size_t)3 * D * D * 2;    // 6 MB  [3072][1024]
    u16* Wpb  = (u16*)p; p += (size_t)D * D * 2;        // 2 MB
    u16* qb   = (u16*)p; p += (size_t)M * D * 2;        // 16 MB
    u16* kb   = (u16*)p; p += (size_t)M * D * 2;        // 16 MB
    u16* vTb  = (u16*)p; p += (size_t)M * D * 2;        // 16 MB  vT[d][b*S+s], ld=M
    u16* vb   = (u16*)p;                                // 16 MB, dead before scores
    float* sc = (float*)p;                              // scores region (overlaps vb)
    u16* attnb = xb;                                    // alias: x dead after QKV

    const size_t fixed = (size_t)p - (size_t)d_ws;
    const size_t vbsz  = (size_t)M * D * 2;
    const size_t sb1   = (size_t)S * S * 4;
    // scores region must hold max(vb, zb*S*S*4); vb dead before first scores GEMM
    int zb = (ws_size >= fixed + 4 * sb1) ? 4 : 1;
    if (zb == 1 && ws_size < fixed + (sb1 > vbsz ? sb1 : vbsz)) zb = 1; // (always true; kept for clarity)

    // fp32 -> bf16
    cvt_bf16_kernel<<<(M * D / 4 + 255) / 256, 256, 0, stream>>>(x, xb, M * D / 4);
    cvt_bf16_kernel<<<(D * D / 4 + 255) / 256, 256, 0, stream>>>(Wq, Wcat, D * D / 4);
    cvt_bf16_kernel<<<(D * D / 4 + 255) / 256, 256, 0, stream>>>(Wk, Wcat + (size_t)D * D, D * D / 4);
    cvt_bf16_kernel<<<(D * D / 4 + 255) / 256, 256, 0, stream>>>(Wv, Wcat + (size_t)2 * D * D, D * D / 4);
    cvt_bf16_kernel<<<(D * D / 4 + 255) / 256, 256, 0, stream>>>(Wp, Wpb, D * D / 4);

    // fused QKV: [q|k|v] = x Wcat^T + [bq|bk|bv]; q scaled by 1/sqrt(D)
    gemm_nt<3, 1, 0, 0><<<dim3(3 * D / BN, M / BM, 1), 256, 0, stream>>>(
        xb, Wcat, qb, bq, kb, bk, vb, bv,
        M, 3 * D, D, D, D, D, 0, 0, 0, 0.03125f);

    // vT = v^T
    transpose16<<<dim3(D / 64, M / 64), 256, 0, stream>>>(vb, vTb, M, D);

    for (int b0 = 0; b0 < B; b0 += zb) {
        // scores = q k^T (lower-triangular tiles only)
        gemm_nt<0, 0, 1, 0><<<dim3(S / BN, S / BM, zb), 256, 0, stream>>>(
            qb + (size_t)b0 * S * D, kb + (size_t)b0 * S * D, sc, nullptr,
            nullptr, nullptr, nullptr, nullptr,
            S, S, D, D, D, S,
            (long long)S * D, (long long)S * D, (long long)S * S, 1.0f);
        // causal softmax, write P (bf16) in place
        softmax_causal_kernel<<<zb * S, 256, 0, stream>>>(sc, S);
        // attn_out = P v   (A = P bf16 ld 2S; B = vT rows, K causally bounded)
        gemm_nt<0, 1, 0, 1><<<dim3(D / BN, S / BM, zb), 256, 0, stream>>>(
            (const u16*)sc, vTb + (size_t)b0 * S, attnb + (size_t)b0 * S * D, nullptr,
            nullptr, nullptr, nullptr, nullptr,
            S, D, S, 2 * S, M, D,
            (long long)2 * S * S, (long long)S, (long long)S * D, 1.0f);
    }

    // out = attn_out Wp^T + bp  (fp32 output)
    gemm_nt<1, 0, 0, 0><<<dim3(D / BN, M / BM, 1), 256, 0, stream>>>(
        attnb, Wpb, d_out, bp, nullptr, nullptr, nullptr, nullptr,
        M, D, D, D, D, D, 0, 0, 0, 1.0f);
}

// Round 3
// 210.296 us; speedup vs baseline: 1.1740x; 1.1740x over previous
//
#include <hip/hip_runtime.h>

#define AS1(p) ((const __attribute__((address_space(1))) void*)(p))
#define AS3(p) ((__attribute__((address_space(3))) void*)(p))

typedef unsigned short u16;
typedef __bf16 bf16x8 __attribute__((ext_vector_type(8)));
typedef short s16x8 __attribute__((ext_vector_type(8)));
typedef float f32x4 __attribute__((ext_vector_type(4)));
typedef unsigned short u16x4 __attribute__((ext_vector_type(4)));
typedef unsigned short u16x8v __attribute__((ext_vector_type(8)));

__device__ __forceinline__ u16 f2bf(float x) {
    unsigned u = __float_as_uint(x);
    unsigned r = (u + 0x7FFFu + ((u >> 16) & 1u)) >> 16;
    return (u16)r;
}

template <typename V8>
__device__ __forceinline__ auto mfma_sel(V8 a, V8 b, f32x4 c, int)
    -> decltype(__builtin_amdgcn_mfma_f32_16x16x32_bf16(a, b, c, 0, 0, 0))
{
    return __builtin_amdgcn_mfma_f32_16x16x32_bf16(a, b, c, 0, 0, 0);
}
template <typename V8>
__device__ __forceinline__ f32x4 mfma_sel(V8 a, V8 b, f32x4 c, long)
{
    s16x8 a2 = __builtin_bit_cast(s16x8, a);
    s16x8 b2 = __builtin_bit_cast(s16x8, b);
    return __builtin_amdgcn_mfma_f32_16x16x32_bf16(a2, b2, c, 0, 0, 0);
}
__device__ __forceinline__ f32x4 mfma16x16x32(bf16x8 a, bf16x8 b, f32x4 c)
{
    return mfma_sel(a, b, c, 0);
}

// ---------------- fp32 -> bf16 convert ----------------
__global__ __launch_bounds__(256) void cvt_bf16_kernel(const float* __restrict__ in,
                                                       u16* __restrict__ out, int n4)
{
    int i = blockIdx.x * 256 + threadIdx.x;
    if (i >= n4) return;
    float4 f = ((const float4*)in)[i];
    u16x4 o;
    o.x = f2bf(f.x); o.y = f2bf(f.y); o.z = f2bf(f.z); o.w = f2bf(f.w);
    ((u16x4*)out)[i] = o;
}

// ---------------- bf16 transpose: in[R][C] -> out[C][R], 64x64 tiles ----------------
__global__ __launch_bounds__(256) void transpose16(const u16* __restrict__ in,
                                                   u16* __restrict__ out, int R, int C)
{
    __shared__ u16 tl[64][65];
    const int tr0 = blockIdx.y * 64, tc0 = blockIdx.x * 64;
    const int t = threadIdx.x;
    const int r = t >> 2, c4 = (t & 3) << 4;

    const u16* src = in + (size_t)(tr0 + r) * C + tc0 + c4;
    u16x8v a0 = *(const u16x8v*)src;
    u16x8v a1 = *(const u16x8v*)(src + 8);
    #pragma unroll
    for (int j = 0; j < 8; ++j) { tl[r][c4 + j] = a0[j]; tl[r][c4 + 8 + j] = a1[j]; }
    __syncthreads();

    u16x8v b0, b1;
    #pragma unroll
    for (int j = 0; j < 8; ++j) { b0[j] = tl[c4 + j][r]; b1[j] = tl[c4 + 8 + j][r]; }
    u16* dst = out + (size_t)(tc0 + r) * R + tr0 + c4;
    *(u16x8v*)dst = b0;
    *(u16x8v*)(dst + 8) = b1;
}

// ============ pipelined NT GEMM: C[m][n] = sum_k A[m][k]*B[n][k] ============
// 128x256 tile, BK=64, 512 threads (2M x 4N waves, 64x64 per wave),
// TRIPLE-buffered LDS (144 KB dynamic) with 2-tile stage lead:
//   iter t: STAGE(t+2 -> buf[(t+2)%3]); ds_read+MFMA from buf[t%3];
//           s_waitcnt vmcnt(6)  (t+1's 6 loads/thread done, t+2's in flight);
//           s_barrier.
// Race proof: STAGE at iter t writes buf[(t+2)%3] == buf[(t-1)%3], whose last
// reads finished before iter t-1's end barrier. Reads at iter t hit buf[t%3],
// staged at iter t-2 and completed by iter t-1's vmcnt(6).
// T2 swizzle (rule 21): linear LDS dest (global_load_lds requirement),
// inverse-XOR'd global SOURCE slot, XOR'd read: slot ^= (row&7).
#define GBM 128
#define GBN 256
#define GBK 64
#define ABUF 16384           // 128*64*2
#define BBUF 32768           // 256*64*2
#define TBUF (ABUF + BBUF)   // 48 KB per buffer
#define LDS_BYTES (3 * TBUF) // 147456

template <int BIAS, int OUTBF16, int CSKIP, int CKB>
__global__ __launch_bounds__(512, 2)
void gemm_nt2(const u16* __restrict__ A, const u16* __restrict__ B,
              void* __restrict__ Cv, const float* __restrict__ bias,
              void* __restrict__ C2, const float* __restrict__ bias2,
              void* __restrict__ C3, const float* __restrict__ bias3,
              int M, int N, int K, int lda, int ldb, int ldc,
              long long sA, long long sB, long long sC, float scale)
{
    extern __shared__ char smem[];

    int by = blockIdx.y;
    if (CKB) by = gridDim.y - 1 - by;       // longest-K blocks first
    const int m0 = by * GBM;
    const int n0 = blockIdx.x * GBN;
    if (CSKIP && n0 > m0 + GBM - 1) return;

    const int z = blockIdx.z;
    A += (size_t)z * (size_t)sA;
    B += (size_t)z * (size_t)sB;

    const int t = threadIdx.x;
    const int lane = t & 63;
    const int w = t >> 6;            // 0..7
    const int wr = w >> 2;           // 0..1 (M)
    const int wc = w & 3;            // 0..3 (N)
    const int fr = lane & 15, fg = lane >> 4;

    int Keff = K;
    if (CKB) { Keff = m0 + GBM; if (Keff > K) Keff = K; }
    const int nk = Keff / GBK;       // always >= 2 for our shapes

    f32x4 acc[4][4] = {};

    auto STAGE = [&](int kt, int buf) {
        const int k0 = kt * GBK;
        char* sb = smem + buf * TBUF;
        #pragma unroll
        for (int i = 0; i < 2; ++i) {      // A: 128x64 = 1024 16B chunks
            int c = t + i * 512;
            int row = c >> 3;
            int sl = (c & 7) ^ (row & 7);  // inverse-swizzled source slot
            __builtin_amdgcn_global_load_lds(
                AS1(A + (size_t)(m0 + row) * lda + k0 + sl * 8),
                AS3(sb + c * 16), 16, 0, 0);
        }
        #pragma unroll
        for (int i = 0; i < 4; ++i) {      // B: 256x64 = 2048 16B chunks
            int c = t + i * 512;
            int row = c >> 3;
            int sl = (c & 7) ^ (row & 7);
            __builtin_amdgcn_global_load_lds(
                AS1(B + (size_t)(n0 + row) * ldb + k0 + sl * 8),
                AS3(sb + ABUF + c * 16), 16, 0, 0);
        }
    };

    // prologue: stage tiles 0,1; wait tile 0 (12 - 6 = tile1 stays in flight)
    STAGE(0, 0);
    STAGE(1, 1);
    asm volatile("s_waitcnt vmcnt(6)" ::: "memory");
    __builtin_amdgcn_s_barrier();

    int cur = 0;
    for (int kt = 0; kt < nk; ++kt) {
        int pb = cur + 2; if (pb >= 3) pb -= 3;
        const bool pf = (kt + 2 < nk);
        if (pf) STAGE(kt + 2, pb);

        const char* la = smem + cur * TBUF;
        const char* lb = la + ABUF;
        #pragma unroll
        for (int kk = 0; kk < GBK; kk += 32) {
            const int cs = (kk >> 3) + fg;     // column 16B-slot 0..7
            bf16x8 af[4], bfv[4];
            #pragma unroll
            for (int mi = 0; mi < 4; ++mi) {
                int row = wr * 64 + mi * 16 + fr;
                af[mi] = *(const bf16x8*)(la + (row << 7) + ((cs ^ (row & 7)) << 4));
            }
            #pragma unroll
            for (int ni = 0; ni < 4; ++ni) {
                int row = wc * 64 + ni * 16 + fr;
                bfv[ni] = *(const bf16x8*)(lb + (row << 7) + ((cs ^ (row & 7)) << 4));
            }
            __builtin_amdgcn_s_setprio(1);
            #pragma unroll
            for (int mi = 0; mi < 4; ++mi)
                #pragma unroll
                for (int ni = 0; ni < 4; ++ni)
                    acc[mi][ni] = mfma16x16x32(af[mi], bfv[ni], acc[mi][ni]);
            __builtin_amdgcn_s_setprio(0);
        }

        if (pf) asm volatile("s_waitcnt vmcnt(6)" ::: "memory");
        else    asm volatile("s_waitcnt vmcnt(0)" ::: "memory");
        __builtin_amdgcn_s_barrier();
        ++cur; if (cur >= 3) cur = 0;
    }

    // ---- epilogue: C/D layout col=lane&15, row=(lane>>4)*4+reg ----
    #pragma unroll
    for (int mi = 0; mi < 4; ++mi) {
        #pragma unroll
        for (int ni = 0; ni < 4; ++ni) {
            int col = n0 + wc * 64 + ni * 16 + fr;
            u16* dst16 = (u16*)Cv;
            float* dst32 = (float*)Cv;
            float bval = 0.f, sc_ = scale;
            int ccol = col;
            if (BIAS == 1) bval = bias[col];
            if (BIAS == 3) {
                int seg = col >> 10; ccol = col & 1023;
                if (seg == 0)      { dst16 = (u16*)Cv; bval = bias[ccol]; }
                else if (seg == 1) { dst16 = (u16*)C2; bval = bias2[ccol]; sc_ = 1.f; }
                else               { dst16 = (u16*)C3; bval = bias3[ccol]; sc_ = 1.f; }
            }
            #pragma unroll
            for (int j = 0; j < 4; ++j) {
                int row = m0 + wr * 64 + mi * 16 + fg * 4 + j;
                float v = (acc[mi][ni][j] + bval) * sc_;
                size_t off = (size_t)z * (size_t)sC + (size_t)row * ldc + ccol;
                if (OUTBF16 || BIAS == 3) dst16[off] = f2bf(v);
                else                      dst32[off] = v;
            }
        }
    }
}

// ---------------- causal softmax, in-place fp32 -> bf16 P ----------------
__device__ __forceinline__ float waveMax(float v) {
    #pragma unroll
    for (int o = 32; o > 0; o >>= 1) v = fmaxf(v, __shfl_xor(v, o));
    return v;
}
__device__ __forceinline__ float waveSum(float v) {
    #pragma unroll
    for (int o = 32; o > 0; o >>= 1) v += __shfl_xor(v, o);
    return v;
}

__global__ __launch_bounds__(256) void softmax_causal_kernel(float* __restrict__ scores, int S)
{
    __shared__ float red[4];
    const int gb = blockIdx.x;
    const int b = gb / S;
    const int i = gb - b * S;
    float* srow = scores + (size_t)b * S * S + (size_t)i * S;
    u16* prow = (u16*)srow;
    const int t = threadIdx.x;
    const int jlim = ((i >> 7) + 1) << 7;

    float vals[8];
    float mx = -1e30f;
    #pragma unroll
    for (int s = 0; s < 8; ++s) {
        int j = t + (s << 8);
        float x = -1e30f;
        if (j <= i) x = srow[j];
        vals[s] = x;
        mx = fmaxf(mx, x);
    }
    mx = waveMax(mx);
    const int wv = t >> 6;
    if ((t & 63) == 0) red[wv] = mx;
    __syncthreads();
    mx = fmaxf(fmaxf(red[0], red[1]), fmaxf(red[2], red[3]));
    __syncthreads();

    float sum = 0.f;
    #pragma unroll
    for (int s = 0; s < 8; ++s) {
        float e = (vals[s] > -1e29f) ? __expf(vals[s] - mx) : 0.f;
        vals[s] = e;
        sum += e;
    }
    sum = waveSum(sum);
    if ((t & 63) == 0) red[wv] = sum;
    __syncthreads();
    sum = red[0] + red[1] + red[2] + red[3];
    const float inv = 1.f / sum;
    __syncthreads();

    #pragma unroll
    for (int s = 0; s < 8; ++s) {
        int j = t + (s << 8);
        if (j < jlim) prow[j] = f2bf(vals[s] * inv);
    }
}

// ---------------- host launcher ----------------
extern "C" void kernel_launch(void* const* d_in, const int* in_sizes, int n_in,
                              void* d_out, int out_size, void* d_ws, size_t ws_size,
                              hipStream_t stream)
{
    (void)in_sizes; (void)n_in; (void)out_size;
    const float* x  = (const float*)d_in[0];
    const float* Wq = (const float*)d_in[1];
    const float* bq = (const float*)d_in[2];
    const float* Wk = (const float*)d_in[3];
    const float* bk = (const float*)d_in[4];
    const float* Wv = (const float*)d_in[5];
    const float* bv = (const float*)d_in[6];
    const float* Wp = (const float*)d_in[7];
    const float* bp = (const float*)d_in[8];

    const int D = 1024, S = 2048, B = 4;
    const int M = B * S; // 8192

    char* p = (char*)d_ws;
    u16* xb   = (u16*)p; p += (size_t)M * D * 2;
    u16* Wcat = (u16*)p; p += (size_t)3 * D * D * 2;
    u16* Wpb  = (u16*)p; p += (size_t)D * D * 2;
    u16* qb   = (u16*)p; p += (size_t)M * D * 2;
    u16* kb   = (u16*)p; p += (size_t)M * D * 2;
    u16* vTb  = (u16*)p; p += (size_t)M * D * 2;   // vT[d][b*S+s], ld=M
    u16* vb   = (u16*)p;                           // dead before scores
    float* sc = (float*)p;                         // scores region (overlaps vb)
    u16* attnb = xb;                               // alias: x dead after QKV

    const size_t fixed = (size_t)p - (size_t)d_ws;
    const size_t sb1   = (size_t)S * S * 4;
    int zb = (ws_size >= fixed + 4 * sb1) ? 4 : 1;

    // raise dynamic-LDS cap for the pipelined GEMM instantiations
    hipFuncSetAttribute((const void*)gemm_nt2<3, 1, 0, 0>,
                        hipFuncAttributeMaxDynamicSharedMemorySize, LDS_BYTES);
    hipFuncSetAttribute((const void*)gemm_nt2<0, 0, 1, 0>,
                        hipFuncAttributeMaxDynamicSharedMemorySize, LDS_BYTES);
    hipFuncSetAttribute((const void*)gemm_nt2<0, 1, 0, 1>,
                        hipFuncAttributeMaxDynamicSharedMemorySize, LDS_BYTES);
    hipFuncSetAttribute((const void*)gemm_nt2<1, 0, 0, 0>,
                        hipFuncAttributeMaxDynamicSharedMemorySize, LDS_BYTES);

    // fp32 -> bf16
    cvt_bf16_kernel<<<(M * D / 4 + 255) / 256, 256, 0, stream>>>(x, xb, M * D / 4);
    cvt_bf16_kernel<<<(D * D / 4 + 255) / 256, 256, 0, stream>>>(Wq, Wcat, D * D / 4);
    cvt_bf16_kernel<<<(D * D / 4 + 255) / 256, 256, 0, stream>>>(Wk, Wcat + (size_t)D * D, D * D / 4);
    cvt_bf16_kernel<<<(D * D / 4 + 255) / 256, 256, 0, stream>>>(Wv, Wcat + (size_t)2 * D * D, D * D / 4);
    cvt_bf16_kernel<<<(D * D / 4 + 255) / 256, 256, 0, stream>>>(Wp, Wpb, D * D / 4);

    // fused QKV: [q|k|v] = x Wcat^T + [bq|bk|bv]; q scaled by 1/sqrt(D)
    gemm_nt2<3, 1, 0, 0><<<dim3(3 * D / GBN, M / GBM, 1), 512, LDS_BYTES, stream>>>(
        xb, Wcat, qb, bq, kb, bk, vb, bv,
        M, 3 * D, D, D, D, D, 0, 0, 0, 0.03125f);

    // vT = v^T
    transpose16<<<dim3(D / 64, M / 64), 256, 0, stream>>>(vb, vTb, M, D);

    for (int b0 = 0; b0 < B; b0 += zb) {
        // scores = q k^T (lower-triangular tiles only), fp32
        gemm_nt2<0, 0, 1, 0><<<dim3(S / GBN, S / GBM, zb), 512, LDS_BYTES, stream>>>(
            qb + (size_t)b0 * S * D, kb + (size_t)b0 * S * D, sc, nullptr,
            nullptr, nullptr, nullptr, nullptr,
            S, S, D, D, D, S,
            (long long)S * D, (long long)S * D, (long long)S * S, 1.0f);
        // causal softmax, write P (bf16) in place
        softmax_causal_kernel<<<zb * S, 256, 0, stream>>>(sc, S);
        // attn_out = P v  (A = P bf16 ld 2S; B = vT rows, K causally bounded)
        gemm_nt2<0, 1, 0, 1><<<dim3(D / GBN, S / GBM, zb), 512, LDS_BYTES, stream>>>(
            (const u16*)sc, vTb + (size_t)b0 * S, attnb + (size_t)b0 * S * D, nullptr,
            nullptr, nullptr, nullptr, nullptr,
            S, D, S, 2 * S, M, D,
            (long long)2 * S * S, (long long)S, (long long)S * D, 1.0f);
    }

    // out = attn_out Wp^T + bp  (fp32 output)
    gemm_nt2<1, 0, 0, 0><<<dim3(D / GBN, M / GBM, 1), 512, LDS_BYTES, stream>>>(
        attnb, Wpb, d_out, bp, nullptr, nullptr, nullptr, nullptr,
        M, D, D, D, D, D, 0, 0, 0, 1.0f);
}